// Round 6
// baseline (380.414 us; speedup 1.0000x reference)
//
#include <hip/hip_runtime.h>
#include <hip/hip_bf16.h>

// GAT 3-layer (PPI-style) on MI355X. fp32 tensors; edge_index (2,E) planar,
// int32/int64 via device flag. R14 -> R15:
// agg kernels were VALU-bound (VALUBusy 59%): p = expf(lrelu(.)) computed
// identically on all 8 lanes of a head (8x redundant transcendental work).
// v2 aggregation: p-phase lane = e*8+h computes ONE (edge,head) p per lane
// per 8-edge chunk; acc-phase fetches p_k via ds_bpermute (__shfl, DS pipe);
// den reduced once at the end via shfl_xor. ~2.6x VALU cut, DS pipe absorbs
// the broadcast. Same trick in agg3 (H=1) with group-local shuffles.

#define CH 4096     // items per partition block
#define CAP 8192    // csrD staging capacity (mean bucket = 4352, 60 sigma headroom)

__device__ __forceinline__ float lrelu(float s) { return (s >= 0.f) ? s : 0.2f * s; }

// ---------------- edge dtype detection: (2,E) planar ----------------

__global__ void detect_kernel(const int* __restrict__ ei, int* __restrict__ flag) {
    int t = threadIdx.x;  // 64 lanes
    int v = ei[2 * t + 1];
    unsigned long long b = __ballot(v == 0);
    if (t == 0) *flag = (b == ~0ULL) ? 1 : 0;
}

__device__ __forceinline__ int edge_at(const void* ei, int is64, long long idx) {
    return is64 ? (int)((const long long*)ei)[idx] : ((const int*)ei)[idx];
}

// ---------------- bucketed CSR build ----------------

__global__ void zero_btot_kernel(int* __restrict__ btot) {
    btot[threadIdx.x] = 0;  // 256 threads
}

// Per-block bucket histogram. Item t in [0,E) = edge t (dst row), [E,E+N) =
// self-loop (dst = t-E). blkhist[bucket*256 + blk], btot[bucket].
__global__ __launch_bounds__(256)
void histA_kernel(const void* __restrict__ ei, const int* __restrict__ flag,
                  int* __restrict__ blkhist, int* __restrict__ btot, int E, int N) {
    __shared__ int h[256];
    int t = threadIdx.x;
    h[t] = 0;
    __syncthreads();
    int is64 = *flag;
    long long base = (long long)blockIdx.x * CH;
    long long tot = (long long)E + N;
#pragma unroll
    for (int i = 0; i < CH / 256; ++i) {
        long long idx = base + t + i * 256;
        if (idx < tot) {
            int dst = (idx < E) ? edge_at(ei, is64, (long long)E + idx) : (int)(idx - E);
            atomicAdd(&h[(dst >> 8) & 255], 1);
        }
    }
    __syncthreads();
    int nb = (N + 255) >> 8;
    if (t < nb) {
        blkhist[t * 256 + blockIdx.x] = h[t];
        atomicAdd(&btot[t], h[t]);
    }
}

// Exclusive scan over bucket totals -> bbase[0..nb], bbase[nb] = total.
__global__ __launch_bounds__(256)
void bucket_scan_kernel(const int* __restrict__ btot, int* __restrict__ bbase,
                        int nb, int total) {
    __shared__ int s[256];
    int t = threadIdx.x;
    int v = (t < nb) ? btot[t] : 0;
    s[t] = v;
    __syncthreads();
#pragma unroll
    for (int off = 1; off < 256; off <<= 1) {
        int u = (t >= off) ? s[t - off] : 0;
        __syncthreads();
        s[t] += u;
        __syncthreads();
    }
    if (t < nb) bbase[t] = s[t] - v;
    if (t == 0) bbase[nb] = total;
}

// Per-bucket exclusive scan across blocks -> absolute run base blkoff.
__global__ __launch_bounds__(256)
void blk_scan_kernel(const int* __restrict__ blkhist, const int* __restrict__ bbase,
                     int* __restrict__ blkoff, int nblk) {
    __shared__ int s[256];
    int t = threadIdx.x;
    int b = blockIdx.x;
    int v = (t < nblk) ? blkhist[b * 256 + t] : 0;
    s[t] = v;
    __syncthreads();
#pragma unroll
    for (int off = 1; off < 256; off <<= 1) {
        int u = (t >= off) ? s[t - off] : 0;
        __syncthreads();
        s[t] += u;
        __syncthreads();
    }
    if (t < nblk) blkoff[b * 256 + t] = bbase[b] + s[t] - v;
}

// Partition: stage the block's CH items in LDS sorted by bucket, then write
// each bucket run contiguously (consecutive lanes -> consecutive addresses).
__global__ __launch_bounds__(256)
void partC_kernel(const void* __restrict__ ei, const int* __restrict__ flag,
                  const int* __restrict__ blkoff, int2* __restrict__ part,
                  int E, int N) {
    __shared__ int h[256];
    __shared__ int lst[256];
    __shared__ int cur[256];
    __shared__ int grb[256];
    __shared__ int ssrc[CH];
    __shared__ int sdst[CH];
    int t = threadIdx.x;
    h[t] = 0;
    __syncthreads();
    int is64 = *flag;
    long long base = (long long)blockIdx.x * CH;
    long long tot = (long long)E + N;
    int msrc[CH / 256], mdst[CH / 256], mb[CH / 256];
#pragma unroll
    for (int i = 0; i < CH / 256; ++i) {
        long long idx = base + t + i * 256;
        if (idx < tot) {
            int s, d;
            if (idx < E) {
                s = edge_at(ei, is64, idx);
                d = edge_at(ei, is64, (long long)E + idx);
            } else {
                s = (int)(idx - E);
                d = s;
            }
            msrc[i] = s;
            mdst[i] = d;
            mb[i] = (d >> 8) & 255;
            atomicAdd(&h[mb[i]], 1);
        } else {
            mb[i] = -1;
        }
    }
    __syncthreads();
    // exclusive scan of h -> lst; cur = lst; grb = absolute run base
    int v = h[t];
    lst[t] = v;
    __syncthreads();
#pragma unroll
    for (int off = 1; off < 256; off <<= 1) {
        int u = (t >= off) ? lst[t - off] : 0;
        __syncthreads();
        lst[t] += u;
        __syncthreads();
    }
    int ex = lst[t] - v;   // each thread touches only its own slot here
    lst[t] = ex;
    cur[t] = ex;
    int nb = (N + 255) >> 8;
    grb[t] = (t < nb) ? blkoff[t * 256 + blockIdx.x] : 0;
    __syncthreads();
#pragma unroll
    for (int i = 0; i < CH / 256; ++i) {
        if (mb[i] >= 0) {
            int slot = atomicAdd(&cur[mb[i]], 1);
            ssrc[slot] = msrc[i];
            sdst[slot] = mdst[i];
        }
    }
    __syncthreads();
    int items = (int)((tot - base < CH) ? (tot - base) : CH);
    for (int r = t; r < items; r += 256) {
        int d = sdst[r];
        int b = (d >> 8) & 255;
        part[grb[b] + (r - lst[b])] = make_int2(ssrc[r], d);
    }
}

// Per-bucket local CSR: counts -> scan -> row_ptr; stage srcs in final order
// in LDS; write the bucket's adj region as one contiguous stream.
__global__ __launch_bounds__(256)
void csrD_kernel(const int2* __restrict__ part, const int* __restrict__ bbase,
                 int* __restrict__ row_ptr, int* __restrict__ adj, int N) {
    __shared__ int cnt[256];
    __shared__ int lst[256];
    __shared__ int cur[256];
    __shared__ int ssrc[CAP];
    int t = threadIdx.x;
    int b = blockIdx.x;
    int lo = bbase[b], hi = bbase[b + 1];
    int n0 = b << 8;
    cnt[t] = 0;
    __syncthreads();
    for (int r = lo + t; r < hi; r += 256) atomicAdd(&cnt[part[r].y & 255], 1);
    __syncthreads();
    int v = cnt[t];
    lst[t] = v;
    __syncthreads();
#pragma unroll
    for (int off = 1; off < 256; off <<= 1) {
        int u = (t >= off) ? lst[t - off] : 0;
        __syncthreads();
        lst[t] += u;
        __syncthreads();
    }
    int ex = lst[t] - v;
    lst[t] = ex;
    cur[t] = ex;
    __syncthreads();
    if (n0 + t < N) row_ptr[n0 + t] = lo + ex;
    if (b == gridDim.x - 1 && t == 0) row_ptr[N] = hi;
    int items = hi - lo;
    if (items <= CAP) {
        for (int r = lo + t; r < hi; r += 256) {
            int2 p = part[r];
            int slot = atomicAdd(&cur[p.y & 255], 1);
            ssrc[slot] = p.x;
        }
        __syncthreads();
        for (int r = t; r < items; r += 256) adj[lo + r] = ssrc[r];
    } else {  // overflow fallback (never for this dataset): unstaged writes
        for (int r = lo + t; r < hi; r += 256) {
            int2 p = part[r];
            int slot = atomicAdd(&cur[p.y & 255], 1);
            adj[lo + slot] = p.x;
        }
    }
}

// ---- w_as = W3 @ a3_src, w_ad = W3 @ a3_dst; and W3 padded to stride 244 ---

__global__ void w3a_kernel(const float* __restrict__ W3,
                           const float* __restrict__ a3s,
                           const float* __restrict__ a3d,
                           float* __restrict__ w_as, float* __restrict__ w_ad) {
    int t = threadIdx.x;  // 128 threads
    if (t >= 128) return;
    int k = t & 63;
    const float* a = (t < 64) ? a3s : a3d;
    float s = 0.f;
    for (int c = 0; c < 242; ++c) s = fmaf(W3[k * 242 + c], a[c], s);
    if (t < 64) w_as[k] = s; else w_ad[k] = s;
}

__global__ __launch_bounds__(256)
void w3pad_kernel(const float* __restrict__ W3, float* __restrict__ W3p) {
    int t = blockIdx.x * blockDim.x + threadIdx.x;  // 64*244
    if (t >= 64 * 244) return;
    int k = t / 244, c = t - k * 244;
    W3p[t] = (c < 242) ? W3[k * 242 + c] : 0.f;
}

// ---------------- GEMM + alpha (layers 1 & 2: 64 cols, H=8, C=8) -----------
// v4: 32 nodes per block staged in LDS (coalesced float4; pad row to K+4 so
// the 4 jj-group broadcast reads hit banks {0,8,16,24} -> conflict-free).

template <int K>
__global__ __launch_bounds__(256)
void gemm_alpha_v4(const float* __restrict__ X, const float* __restrict__ W,
                   const float* __restrict__ a_src, const float* __restrict__ a_dst,
                   float* __restrict__ XW, float* __restrict__ As, float* __restrict__ Ad,
                   int N) {
    constexpr int S = K + 4;        // padded LDS row stride (floats)
    constexpr int F4R = K / 4;      // float4 per row
    __shared__ float xs[32][S];
    int t = threadIdx.x;
    int block0 = blockIdx.x * 32;

    for (int i = t; i < 32 * F4R; i += 256) {
        int row = i / F4R, c4 = i - row * F4R;
        int node = block0 + row;
        float4 v = (node < N) ? *(const float4*)(X + (size_t)node * K + c4 * 4)
                              : make_float4(0.f, 0.f, 0.f, 0.f);
        *(float4*)(&xs[row][c4 * 4]) = v;
    }
    __syncthreads();

    int wave = t >> 6, lane = t & 63;
    int jj = lane >> 4, cc = lane & 15;
    int r0 = wave * 8 + jj * 2;     // local node pair
    int base = block0 + r0;

    float4 o0 = make_float4(0.f, 0.f, 0.f, 0.f);
    float4 o1 = make_float4(0.f, 0.f, 0.f, 0.f);

    const float* wp = W + cc * 4;
#pragma unroll 2
    for (int k = 0; k < K; k += 4) {
        float4 w0 = *(const float4*)(wp + (size_t)(k + 0) * 64);
        float4 w1 = *(const float4*)(wp + (size_t)(k + 1) * 64);
        float4 w2 = *(const float4*)(wp + (size_t)(k + 2) * 64);
        float4 w3 = *(const float4*)(wp + (size_t)(k + 3) * 64);
        float4 m0 = *(const float4*)(&xs[r0][k]);
        float4 m1 = *(const float4*)(&xs[r0 + 1][k]);

        o0.x = fmaf(m0.x, w0.x, o0.x);
        o0.y = fmaf(m0.x, w0.y, o0.y);
        o0.z = fmaf(m0.x, w0.z, o0.z);
        o0.w = fmaf(m0.x, w0.w, o0.w);
        o0.x = fmaf(m0.y, w1.x, o0.x);
        o0.y = fmaf(m0.y, w1.y, o0.y);
        o0.z = fmaf(m0.y, w1.z, o0.z);
        o0.w = fmaf(m0.y, w1.w, o0.w);
        o0.x = fmaf(m0.z, w2.x, o0.x);
        o0.y = fmaf(m0.z, w2.y, o0.y);
        o0.z = fmaf(m0.z, w2.z, o0.z);
        o0.w = fmaf(m0.z, w2.w, o0.w);
        o0.x = fmaf(m0.w, w3.x, o0.x);
        o0.y = fmaf(m0.w, w3.y, o0.y);
        o0.z = fmaf(m0.w, w3.z, o0.z);
        o0.w = fmaf(m0.w, w3.w, o0.w);

        o1.x = fmaf(m1.x, w0.x, o1.x);
        o1.y = fmaf(m1.x, w0.y, o1.y);
        o1.z = fmaf(m1.x, w0.z, o1.z);
        o1.w = fmaf(m1.x, w0.w, o1.w);
        o1.x = fmaf(m1.y, w1.x, o1.x);
        o1.y = fmaf(m1.y, w1.y, o1.y);
        o1.z = fmaf(m1.y, w1.z, o1.z);
        o1.w = fmaf(m1.y, w1.w, o1.w);
        o1.x = fmaf(m1.z, w2.x, o1.x);
        o1.y = fmaf(m1.z, w2.y, o1.y);
        o1.z = fmaf(m1.z, w2.z, o1.z);
        o1.w = fmaf(m1.z, w2.w, o1.w);
        o1.x = fmaf(m1.w, w3.x, o1.x);
        o1.y = fmaf(m1.w, w3.y, o1.y);
        o1.z = fmaf(m1.w, w3.z, o1.z);
        o1.w = fmaf(m1.w, w3.w, o1.w);
    }

    // epilogue: store xw + per-head alpha partials. Lane's 4 cols sit inside
    // head h = cc>>1; pair-reduce (cc even/odd) covers the 8 cols of the head.
    float4 av = *(const float4*)(a_src + cc * 4);
    float4 dv = *(const float4*)(a_dst + cc * 4);

    if (base < N) {
        *(float4*)(XW + (size_t)base * 64 + cc * 4) = o0;
        float s = o0.x * av.x + o0.y * av.y + o0.z * av.z + o0.w * av.w;
        float d = o0.x * dv.x + o0.y * dv.y + o0.z * dv.z + o0.w * dv.w;
        s += __shfl_xor(s, 1);
        d += __shfl_xor(d, 1);
        if ((cc & 1) == 0) {
            As[base * 8 + (cc >> 1)] = s;
            Ad[base * 8 + (cc >> 1)] = d;
        }
    }
    if (base + 1 < N) {
        *(float4*)(XW + (size_t)(base + 1) * 64 + cc * 4) = o1;
        float s = o1.x * av.x + o1.y * av.y + o1.z * av.z + o1.w * av.w;
        float d = o1.x * dv.x + o1.y * dv.y + o1.z * dv.z + o1.w * dv.w;
        s += __shfl_xor(s, 1);
        d += __shfl_xor(d, 1);
        if ((cc & 1) == 0) {
            As[(base + 1) * 8 + (cc >> 1)] = s;
            Ad[(base + 1) * 8 + (cc >> 1)] = d;
        }
    }
}

// ---------------- Aggregation v2 (layers 1 & 2: H=8, C=8) ------------------
// One wave per dst node. p-phase: lane = e*8+h computes ONE (edge,head)
// p = expf(lrelu(As[src][h] + Ad[node][h])) per 8-edge chunk (no redundancy);
// den accumulates per lane, reduced once at the end (shfl_xor 8/16/32).
// acc-phase: lane = h*8+c (h = lane>>3); p_k fetched via __shfl from p-lane
// k*8+h (ds_bpermute, DS pipe); XW row loads + 2-chain fma unchanged.

template <bool WITH_A3>
__global__ __launch_bounds__(256)
void agg_h8c8_v2(const float* __restrict__ XW, const float* __restrict__ As,
                 const float* __restrict__ Ad, const int* __restrict__ row_ptr,
                 const int* __restrict__ adj, const float* __restrict__ bias,
                 float* __restrict__ OUT,
                 const float* __restrict__ w_as, const float* __restrict__ w_ad,
                 float* __restrict__ As3, float* __restrict__ Ad3, int N) {
    int wave = threadIdx.x >> 6, lane = threadIdx.x & 63;
    int node = blockIdx.x * 4 + wave;
    if (node >= N) return;
    int beg = row_ptr[node], end = row_ptr[node + 1];
    int eP = lane >> 3, hP = lane & 7;   // p-phase coords
    int hA = lane >> 3;                  // acc-phase head
    float adp = Ad[node * 8 + hP];
    float bv = bias[lane];

    float den_part = 0.f;
    float acc0 = 0.f, acc1 = 0.f;
    int idx = beg;
    for (; idx + 8 <= end; idx += 8) {
        // p-phase: one (e,h) per lane
        int se = adj[idx + eP];
        float ec = As[(size_t)se * 8 + hP];
        float p = __expf(lrelu(ec + adp));
        den_part += p;
        // acc-phase: wave-uniform src indices, row loads, bpermute broadcast
        int s0 = adj[idx + 0], s1 = adj[idx + 1], s2 = adj[idx + 2], s3 = adj[idx + 3];
        int s4 = adj[idx + 4], s5 = adj[idx + 5], s6 = adj[idx + 6], s7 = adj[idx + 7];
        float x0 = XW[(size_t)s0 * 64 + lane];
        float x1 = XW[(size_t)s1 * 64 + lane];
        float x2 = XW[(size_t)s2 * 64 + lane];
        float x3 = XW[(size_t)s3 * 64 + lane];
        float x4 = XW[(size_t)s4 * 64 + lane];
        float x5 = XW[(size_t)s5 * 64 + lane];
        float x6 = XW[(size_t)s6 * 64 + lane];
        float x7 = XW[(size_t)s7 * 64 + lane];
        float p0 = __shfl(p, 0 * 8 + hA);
        float p1 = __shfl(p, 1 * 8 + hA);
        float p2 = __shfl(p, 2 * 8 + hA);
        float p3 = __shfl(p, 3 * 8 + hA);
        float p4 = __shfl(p, 4 * 8 + hA);
        float p5 = __shfl(p, 5 * 8 + hA);
        float p6 = __shfl(p, 6 * 8 + hA);
        float p7 = __shfl(p, 7 * 8 + hA);
        acc0 = fmaf(p0, x0, acc0);
        acc1 = fmaf(p1, x1, acc1);
        acc0 = fmaf(p2, x2, acc0);
        acc1 = fmaf(p3, x3, acc1);
        acc0 = fmaf(p4, x4, acc0);
        acc1 = fmaf(p5, x5, acc1);
        acc0 = fmaf(p6, x6, acc0);
        acc1 = fmaf(p7, x7, acc1);
    }
    int rem = end - idx;
    if (rem > 0) {
        int se = adj[idx + (eP < rem ? eP : rem - 1)];
        float ec = As[(size_t)se * 8 + hP];
        float p = (eP < rem) ? __expf(lrelu(ec + adp)) : 0.f;
        den_part += p;
#pragma unroll
        for (int k = 0; k < 8; ++k) {
            if (k < rem) {  // wave-uniform branch
                int sk = adj[idx + k];
                float xk = XW[(size_t)sk * 64 + lane];
                float pk = __shfl(p, k * 8 + hA);
                acc0 = fmaf(pk, xk, acc0);
            }
        }
    }
    float acc = acc0 + acc1;
    // den: sum over e-slots (stride-8 lanes), then route to acc layout
    den_part += __shfl_xor(den_part, 8);
    den_part += __shfl_xor(den_part, 16);
    den_part += __shfl_xor(den_part, 32);   // lane holds den[lane&7]
    float den = __shfl(den_part, hA);       // acc lane wants den[hA]

    float v = fmaxf(acc / (den + 1e-16f) + bv, 0.f);
    OUT[(size_t)node * 64 + lane] = v;

    if (WITH_A3) {
        float s3v = v * w_as[lane];
        float d3v = v * w_ad[lane];
#pragma unroll
        for (int m = 1; m <= 32; m <<= 1) {
            s3v += __shfl_xor(s3v, m);
            d3v += __shfl_xor(d3v, m);
        }
        if (lane == 0) {
            As3[node] = s3v;
            Ad3[node] = d3v;
        }
    }
}

// ---------------- Layer 3 aggregation v2 (H=1, 64 cols) --------------------
// p replicated per aligned 8-lane group (e = lane&7): group-local reduce
// (xor 1/2/4) gives every lane the full den; p_k broadcast group-locally.

__global__ __launch_bounds__(256)
void agg3msg_v2(const float* __restrict__ H2, const float* __restrict__ As3,
                const float* __restrict__ Ad3, const int* __restrict__ row_ptr,
                const int* __restrict__ adj, float* __restrict__ MSG, int N) {
    int wave = threadIdx.x >> 6, lane = threadIdx.x & 63;
    int node = blockIdx.x * 4 + wave;
    if (node >= N) return;
    int beg = row_ptr[node], end = row_ptr[node + 1];
    float ad = Ad3[node];
    int eP = lane & 7;
    int gbase = lane & 56;  // group-local shuffle base

    float den_part = 0.f;
    float acc0 = 0.f, acc1 = 0.f;
    int idx = beg;
    for (; idx + 8 <= end; idx += 8) {
        int se = adj[idx + eP];
        float p = __expf(lrelu(As3[se] + ad));
        den_part += p;
        int s0 = adj[idx + 0], s1 = adj[idx + 1], s2 = adj[idx + 2], s3 = adj[idx + 3];
        int s4 = adj[idx + 4], s5 = adj[idx + 5], s6 = adj[idx + 6], s7 = adj[idx + 7];
        float x0 = H2[(size_t)s0 * 64 + lane];
        float x1 = H2[(size_t)s1 * 64 + lane];
        float x2 = H2[(size_t)s2 * 64 + lane];
        float x3 = H2[(size_t)s3 * 64 + lane];
        float x4 = H2[(size_t)s4 * 64 + lane];
        float x5 = H2[(size_t)s5 * 64 + lane];
        float x6 = H2[(size_t)s6 * 64 + lane];
        float x7 = H2[(size_t)s7 * 64 + lane];
        float p0 = __shfl(p, gbase + 0);
        float p1 = __shfl(p, gbase + 1);
        float p2 = __shfl(p, gbase + 2);
        float p3 = __shfl(p, gbase + 3);
        float p4 = __shfl(p, gbase + 4);
        float p5 = __shfl(p, gbase + 5);
        float p6 = __shfl(p, gbase + 6);
        float p7 = __shfl(p, gbase + 7);
        acc0 = fmaf(p0, x0, acc0);
        acc1 = fmaf(p1, x1, acc1);
        acc0 = fmaf(p2, x2, acc0);
        acc1 = fmaf(p3, x3, acc1);
        acc0 = fmaf(p4, x4, acc0);
        acc1 = fmaf(p5, x5, acc1);
        acc0 = fmaf(p6, x6, acc0);
        acc1 = fmaf(p7, x7, acc1);
    }
    int rem = end - idx;
    if (rem > 0) {
        int se = adj[idx + (eP < rem ? eP : rem - 1)];
        float p = (eP < rem) ? __expf(lrelu(As3[se] + ad)) : 0.f;
        den_part += p;
#pragma unroll
        for (int k = 0; k < 8; ++k) {
            if (k < rem) {  // wave-uniform branch
                int sk = adj[idx + k];
                float xk = H2[(size_t)sk * 64 + lane];
                float pk = __shfl(p, gbase + k);
                acc0 = fmaf(pk, xk, acc0);
            }
        }
    }
    float acc = acc0 + acc1;
    den_part += __shfl_xor(den_part, 1);
    den_part += __shfl_xor(den_part, 2);
    den_part += __shfl_xor(den_part, 4);  // every lane: full den
    MSG[(size_t)node * 64 + lane] = acc / (den_part + 1e-16f);
}

// ---------------- gemm3 v2: OUT = softmax_pairs(relu(MSG @ W3 + b3)) -------

__global__ __launch_bounds__(256)
void gemm3_kernel(const float* __restrict__ MSG, const float* __restrict__ W3p,
                  const float* __restrict__ bias, float* __restrict__ OUT, int N) {
    __shared__ float msh[4][8][64];
    int wave = threadIdx.x >> 6, lane = threadIdx.x & 63;
    int base = blockIdx.x * 32 + wave * 8;

#pragma unroll
    for (int j = 0; j < 8; ++j) {
        int node = base + j;
        msh[wave][j][lane] = (node < N) ? MSG[(size_t)node * 64 + lane] : 0.f;
    }
    // same-wave LDS RAW: DS pipe in-order, compiler inserts lgkmcnt wait

    int c0 = lane * 4;  // lanes 0..60 carry channels; 61-63 idle
    if (c0 < 242) {
        float o[8][4];
#pragma unroll
        for (int j = 0; j < 8; ++j)
#pragma unroll
            for (int q = 0; q < 4; ++q) o[j][q] = 0.f;

#pragma unroll 4
        for (int k = 0; k < 64; k += 4) {
            float4 w0 = *(const float4*)(W3p + (size_t)(k + 0) * 244 + c0);
            float4 w1 = *(const float4*)(W3p + (size_t)(k + 1) * 244 + c0);
            float4 w2 = *(const float4*)(W3p + (size_t)(k + 2) * 244 + c0);
            float4 w3 = *(const float4*)(W3p + (size_t)(k + 3) * 244 + c0);
#pragma unroll
            for (int j = 0; j < 8; ++j) {
                float4 m = *(const float4*)(&msh[wave][j][k]);
                o[j][0] = fmaf(m.x, w0.x, o[j][0]);
                o[j][1] = fmaf(m.x, w0.y, o[j][1]);
                o[j][2] = fmaf(m.x, w0.z, o[j][2]);
                o[j][3] = fmaf(m.x, w0.w, o[j][3]);
                o[j][0] = fmaf(m.y, w1.x, o[j][0]);
                o[j][1] = fmaf(m.y, w1.y, o[j][1]);
                o[j][2] = fmaf(m.y, w1.z, o[j][2]);
                o[j][3] = fmaf(m.y, w1.w, o[j][3]);
                o[j][0] = fmaf(m.z, w2.x, o[j][0]);
                o[j][1] = fmaf(m.z, w2.y, o[j][1]);
                o[j][2] = fmaf(m.z, w2.z, o[j][2]);
                o[j][3] = fmaf(m.z, w2.w, o[j][3]);
                o[j][0] = fmaf(m.w, w3.x, o[j][0]);
                o[j][1] = fmaf(m.w, w3.y, o[j][1]);
                o[j][2] = fmaf(m.w, w3.z, o[j][2]);
                o[j][3] = fmaf(m.w, w3.w, o[j][3]);
            }
        }

        float b0 = bias[c0], b1v = bias[c0 + 1];
        float b2v = (c0 + 2 < 242) ? bias[c0 + 2] : 0.f;
        float b3v = (c0 + 3 < 242) ? bias[c0 + 3] : 0.f;
#pragma unroll
        for (int j = 0; j < 8; ++j) {
            int node = base + j;
            if (node >= N) break;
            size_t out_base = (size_t)node * 242 + c0;
            float v0 = fmaxf(o[j][0] + b0, 0.f);
            float v1 = fmaxf(o[j][1] + b1v, 0.f);
            float m01 = fmaxf(v0, v1);
            float e0 = __expf(v0 - m01), e1 = __expf(v1 - m01);
            float r01 = 1.f / (e0 + e1);
            OUT[out_base]     = e0 * r01;
            OUT[out_base + 1] = e1 * r01;
            if (c0 + 2 < 242) {
                float v2 = fmaxf(o[j][2] + b2v, 0.f);
                float v3 = fmaxf(o[j][3] + b3v, 0.f);
                float m23 = fmaxf(v2, v3);
                float e2 = __expf(v2 - m23), e3 = __expf(v3 - m23);
                float r23 = 1.f / (e2 + e3);
                OUT[out_base + 2] = e2 * r23;
                OUT[out_base + 3] = e3 * r23;
            }
        }
    }
}

// ---------------- launch ----------------

extern "C" void kernel_launch(void* const* d_in, const int* in_sizes, int n_in,
                              void* d_out, int out_size, void* d_ws, size_t ws_size,
                              hipStream_t stream) {
    const float* x   = (const float*)d_in[0];
    const void*  ei  = d_in[1];
    const float* W1  = (const float*)d_in[2];
    const float* a1s = (const float*)d_in[3];
    const float* a1d = (const float*)d_in[4];
    const float* b1  = (const float*)d_in[5];
    const float* W2  = (const float*)d_in[6];
    const float* a2s = (const float*)d_in[7];
    const float* a2d = (const float*)d_in[8];
    const float* b2  = (const float*)d_in[9];
    const float* W3  = (const float*)d_in[10];
    const float* a3s = (const float*)d_in[11];
    const float* a3d = (const float*)d_in[12];
    const float* b3  = (const float*)d_in[13];
    float* out = (float*)d_out;

    const int N = in_sizes[0] / 128;  // 50000
    const int E = in_sizes[1] / 2;    // 800000

    char* w = (char*)d_ws;
    auto alloc = [&](size_t bytes) {
        char* p = w;
        w += (bytes + 255) & ~(size_t)255;
        return p;
    };
    int*   flag    = (int*)alloc(4);
    int*   row_ptr = (int*)alloc(((size_t)N + 1) * 4);
    int*   adj     = (int*)alloc((size_t)(E + N) * 4);
    int*   btot    = (int*)alloc(256 * 4);
    int*   bbase   = (int*)alloc(257 * 4);
    float* As      = (float*)alloc((size_t)N * 8 * 4);
    float* Ad      = (float*)alloc((size_t)N * 8 * 4);
    float* As3     = (float*)alloc((size_t)N * 4);
    float* Ad3     = (float*)alloc((size_t)N * 4);
    float* w_as    = (float*)alloc(64 * 4);
    float* w_ad    = (float*)alloc(64 * 4);
    float* W3p     = (float*)alloc((size_t)64 * 244 * 4);
    float* bufA    = (float*)alloc((size_t)N * 64 * 4);
    float* bufB    = (float*)alloc((size_t)N * 64 * 4);
    // CSR scratch aliased into bufA (12.8MB): part 6.8MB @0, blkhist 256KB @7MB,
    // blkoff 256KB @7.25MB. All dead before gemm_alpha first writes bufA.
    int2*  part    = (int2*)bufA;
    int*   blkhist = (int*)((char*)bufA + (size_t)7 * 1024 * 1024);
    int*   blkoff  = (int*)((char*)bufA + (size_t)7 * 1024 * 1024 + 256 * 1024);

    int tot  = E + N;                       // 850000
    int nblk = (tot + CH - 1) / CH;         // 208 <= 256
    int nb   = (N + 255) >> 8;              // 196 <= 256

    // CSR build (bucketed counting sort; includes self-loops)
    detect_kernel<<<1, 64, 0, stream>>>((const int*)ei, flag);
    zero_btot_kernel<<<1, 256, 0, stream>>>(btot);
    histA_kernel<<<nblk, 256, 0, stream>>>(ei, flag, blkhist, btot, E, N);
    bucket_scan_kernel<<<1, 256, 0, stream>>>(btot, bbase, nb, tot);
    blk_scan_kernel<<<nb, 256, 0, stream>>>(blkhist, bbase, blkoff, nblk);
    partC_kernel<<<nblk, 256, 0, stream>>>(ei, flag, blkoff, part, E, N);
    csrD_kernel<<<nb, 256, 0, stream>>>(part, bbase, row_ptr, adj, N);
    w3a_kernel<<<1, 128, 0, stream>>>(W3, a3s, a3d, w_as, w_ad);
    w3pad_kernel<<<(64 * 244 + 255) / 256, 256, 0, stream>>>(W3, W3p);

    int nb4 = (N + 3) / 4;
    int nb32 = (N + 31) / 32;

    // Layer 1: x -> bufA (xw1), agg -> bufB (h1)
    gemm_alpha_v4<128><<<nb32, 256, 0, stream>>>(x, W1, a1s, a1d, bufA, As, Ad, N);
    agg_h8c8_v2<false><<<nb4, 256, 0, stream>>>(bufA, As, Ad, row_ptr, adj, b1, bufB,
                                                nullptr, nullptr, nullptr, nullptr, N);
    // Layer 2: bufB -> bufB in-place (xw2), agg -> bufA (h2) + As3/Ad3 epilogue
    gemm_alpha_v4<64><<<nb32, 256, 0, stream>>>(bufB, W2, a2s, a2d, bufB, As, Ad, N);
    agg_h8c8_v2<true><<<nb4, 256, 0, stream>>>(bufB, As, Ad, row_ptr, adj, b2, bufA,
                                               w_as, w_ad, As3, Ad3, N);
    // Layer 3: h-space aggregation (bufA -> bufB), then gemm3 v2 -> out
    agg3msg_v2<<<nb4, 256, 0, stream>>>(bufA, As3, Ad3, row_ptr, adj, bufB, N);
    gemm3_kernel<<<nb32, 256, 0, stream>>>(bufB, W3p, b3, out, N);
}

// Round 7
// 365.939 us; speedup vs baseline: 1.0396x; 1.0396x over previous
//
#include <hip/hip_runtime.h>
#include <hip/hip_bf16.h>
#include <hip/hip_fp16.h>

// GAT 3-layer (PPI-style) on MI355X. fp32 tensors; edge_index (2,E) planar,
// int32/int64 via device flag. R15 -> R16:
// agg FETCH 109.6MB == 8 XCDs x 12.8MB XW buffer: random pull-gather makes
// each non-coherent L2 stream the whole buffer -> we are AT the structural
// traffic floor. Only lever: fewer bytes/row. XW1/XW2/H2 stored as fp16
// (gather rows 256B->128B, floor ~55MB); all accumulation + As/Ad/As3/Ad3
// and contiguous buffers stay fp32. Lifetimes: XW1h@bufA[0], XW2h@bufA[6.4M],
// h2h reuses bufA[0], MSG fp32 reuses bufB -- footprint unchanged (proven).

#define CH 4096     // items per partition block
#define CAP 8192    // csrD staging capacity (mean bucket = 4352, 60 sigma headroom)

__device__ __forceinline__ float lrelu(float s) { return (s >= 0.f) ? s : 0.2f * s; }

// ---------------- edge dtype detection: (2,E) planar ----------------

__global__ void detect_kernel(const int* __restrict__ ei, int* __restrict__ flag) {
    int t = threadIdx.x;  // 64 lanes
    int v = ei[2 * t + 1];
    unsigned long long b = __ballot(v == 0);
    if (t == 0) *flag = (b == ~0ULL) ? 1 : 0;
}

__device__ __forceinline__ int edge_at(const void* ei, int is64, long long idx) {
    return is64 ? (int)((const long long*)ei)[idx] : ((const int*)ei)[idx];
}

// ---------------- bucketed CSR build ----------------

__global__ void zero_btot_kernel(int* __restrict__ btot) {
    btot[threadIdx.x] = 0;  // 256 threads
}

__global__ __launch_bounds__(256)
void histA_kernel(const void* __restrict__ ei, const int* __restrict__ flag,
                  int* __restrict__ blkhist, int* __restrict__ btot, int E, int N) {
    __shared__ int h[256];
    int t = threadIdx.x;
    h[t] = 0;
    __syncthreads();
    int is64 = *flag;
    long long base = (long long)blockIdx.x * CH;
    long long tot = (long long)E + N;
#pragma unroll
    for (int i = 0; i < CH / 256; ++i) {
        long long idx = base + t + i * 256;
        if (idx < tot) {
            int dst = (idx < E) ? edge_at(ei, is64, (long long)E + idx) : (int)(idx - E);
            atomicAdd(&h[(dst >> 8) & 255], 1);
        }
    }
    __syncthreads();
    int nb = (N + 255) >> 8;
    if (t < nb) {
        blkhist[t * 256 + blockIdx.x] = h[t];
        atomicAdd(&btot[t], h[t]);
    }
}

__global__ __launch_bounds__(256)
void bucket_scan_kernel(const int* __restrict__ btot, int* __restrict__ bbase,
                        int nb, int total) {
    __shared__ int s[256];
    int t = threadIdx.x;
    int v = (t < nb) ? btot[t] : 0;
    s[t] = v;
    __syncthreads();
#pragma unroll
    for (int off = 1; off < 256; off <<= 1) {
        int u = (t >= off) ? s[t - off] : 0;
        __syncthreads();
        s[t] += u;
        __syncthreads();
    }
    if (t < nb) bbase[t] = s[t] - v;
    if (t == 0) bbase[nb] = total;
}

__global__ __launch_bounds__(256)
void blk_scan_kernel(const int* __restrict__ blkhist, const int* __restrict__ bbase,
                     int* __restrict__ blkoff, int nblk) {
    __shared__ int s[256];
    int t = threadIdx.x;
    int b = blockIdx.x;
    int v = (t < nblk) ? blkhist[b * 256 + t] : 0;
    s[t] = v;
    __syncthreads();
#pragma unroll
    for (int off = 1; off < 256; off <<= 1) {
        int u = (t >= off) ? s[t - off] : 0;
        __syncthreads();
        s[t] += u;
        __syncthreads();
    }
    if (t < nblk) blkoff[b * 256 + t] = bbase[b] + s[t] - v;
}

__global__ __launch_bounds__(256)
void partC_kernel(const void* __restrict__ ei, const int* __restrict__ flag,
                  const int* __restrict__ blkoff, int2* __restrict__ part,
                  int E, int N) {
    __shared__ int h[256];
    __shared__ int lst[256];
    __shared__ int cur[256];
    __shared__ int grb[256];
    __shared__ int ssrc[CH];
    __shared__ int sdst[CH];
    int t = threadIdx.x;
    h[t] = 0;
    __syncthreads();
    int is64 = *flag;
    long long base = (long long)blockIdx.x * CH;
    long long tot = (long long)E + N;
    int msrc[CH / 256], mdst[CH / 256], mb[CH / 256];
#pragma unroll
    for (int i = 0; i < CH / 256; ++i) {
        long long idx = base + t + i * 256;
        if (idx < tot) {
            int s, d;
            if (idx < E) {
                s = edge_at(ei, is64, idx);
                d = edge_at(ei, is64, (long long)E + idx);
            } else {
                s = (int)(idx - E);
                d = s;
            }
            msrc[i] = s;
            mdst[i] = d;
            mb[i] = (d >> 8) & 255;
            atomicAdd(&h[mb[i]], 1);
        } else {
            mb[i] = -1;
        }
    }
    __syncthreads();
    int v = h[t];
    lst[t] = v;
    __syncthreads();
#pragma unroll
    for (int off = 1; off < 256; off <<= 1) {
        int u = (t >= off) ? lst[t - off] : 0;
        __syncthreads();
        lst[t] += u;
        __syncthreads();
    }
    int ex = lst[t] - v;
    lst[t] = ex;
    cur[t] = ex;
    int nb = (N + 255) >> 8;
    grb[t] = (t < nb) ? blkoff[t * 256 + blockIdx.x] : 0;
    __syncthreads();
#pragma unroll
    for (int i = 0; i < CH / 256; ++i) {
        if (mb[i] >= 0) {
            int slot = atomicAdd(&cur[mb[i]], 1);
            ssrc[slot] = msrc[i];
            sdst[slot] = mdst[i];
        }
    }
    __syncthreads();
    int items = (int)((tot - base < CH) ? (tot - base) : CH);
    for (int r = t; r < items; r += 256) {
        int d = sdst[r];
        int b = (d >> 8) & 255;
        part[grb[b] + (r - lst[b])] = make_int2(ssrc[r], d);
    }
}

__global__ __launch_bounds__(256)
void csrD_kernel(const int2* __restrict__ part, const int* __restrict__ bbase,
                 int* __restrict__ row_ptr, int* __restrict__ adj, int N) {
    __shared__ int cnt[256];
    __shared__ int lst[256];
    __shared__ int cur[256];
    __shared__ int ssrc[CAP];
    int t = threadIdx.x;
    int b = blockIdx.x;
    int lo = bbase[b], hi = bbase[b + 1];
    int n0 = b << 8;
    cnt[t] = 0;
    __syncthreads();
    for (int r = lo + t; r < hi; r += 256) atomicAdd(&cnt[part[r].y & 255], 1);
    __syncthreads();
    int v = cnt[t];
    lst[t] = v;
    __syncthreads();
#pragma unroll
    for (int off = 1; off < 256; off <<= 1) {
        int u = (t >= off) ? lst[t - off] : 0;
        __syncthreads();
        lst[t] += u;
        __syncthreads();
    }
    int ex = lst[t] - v;
    lst[t] = ex;
    cur[t] = ex;
    __syncthreads();
    if (n0 + t < N) row_ptr[n0 + t] = lo + ex;
    if (b == gridDim.x - 1 && t == 0) row_ptr[N] = hi;
    int items = hi - lo;
    if (items <= CAP) {
        for (int r = lo + t; r < hi; r += 256) {
            int2 p = part[r];
            int slot = atomicAdd(&cur[p.y & 255], 1);
            ssrc[slot] = p.x;
        }
        __syncthreads();
        for (int r = t; r < items; r += 256) adj[lo + r] = ssrc[r];
    } else {  // overflow fallback (never for this dataset): unstaged writes
        for (int r = lo + t; r < hi; r += 256) {
            int2 p = part[r];
            int slot = atomicAdd(&cur[p.y & 255], 1);
            adj[lo + slot] = p.x;
        }
    }
}

// ---- w_as = W3 @ a3_src, w_ad = W3 @ a3_dst; and W3 padded to stride 244 ---

__global__ void w3a_kernel(const float* __restrict__ W3,
                           const float* __restrict__ a3s,
                           const float* __restrict__ a3d,
                           float* __restrict__ w_as, float* __restrict__ w_ad) {
    int t = threadIdx.x;  // 128 threads
    if (t >= 128) return;
    int k = t & 63;
    const float* a = (t < 64) ? a3s : a3d;
    float s = 0.f;
    for (int c = 0; c < 242; ++c) s = fmaf(W3[k * 242 + c], a[c], s);
    if (t < 64) w_as[k] = s; else w_ad[k] = s;
}

__global__ __launch_bounds__(256)
void w3pad_kernel(const float* __restrict__ W3, float* __restrict__ W3p) {
    int t = blockIdx.x * blockDim.x + threadIdx.x;  // 64*244
    if (t >= 64 * 244) return;
    int k = t / 244, c = t - k * 244;
    W3p[t] = (c < 242) ? W3[k * 242 + c] : 0.f;
}

// ---------------- GEMM + alpha (layers 1 & 2) — fp16 XW output -------------
// v5: v4 structure (32-node LDS stage, padded rows, broadcast reads) but XW
// stored as fp16 (one uint2 = 4 halves per lane). As/Ad from fp32 accs.

template <int K>
__global__ __launch_bounds__(256)
void gemm_alpha_v5(const float* __restrict__ X, const float* __restrict__ W,
                   const float* __restrict__ a_src, const float* __restrict__ a_dst,
                   __half* __restrict__ XWh, float* __restrict__ As, float* __restrict__ Ad,
                   int N) {
    constexpr int S = K + 4;        // padded LDS row stride (floats)
    constexpr int F4R = K / 4;      // float4 per row
    __shared__ float xs[32][S];
    int t = threadIdx.x;
    int block0 = blockIdx.x * 32;

    for (int i = t; i < 32 * F4R; i += 256) {
        int row = i / F4R, c4 = i - row * F4R;
        int node = block0 + row;
        float4 v = (node < N) ? *(const float4*)(X + (size_t)node * K + c4 * 4)
                              : make_float4(0.f, 0.f, 0.f, 0.f);
        *(float4*)(&xs[row][c4 * 4]) = v;
    }
    __syncthreads();

    int wave = t >> 6, lane = t & 63;
    int jj = lane >> 4, cc = lane & 15;
    int r0 = wave * 8 + jj * 2;     // local node pair
    int base = block0 + r0;

    float4 o0 = make_float4(0.f, 0.f, 0.f, 0.f);
    float4 o1 = make_float4(0.f, 0.f, 0.f, 0.f);

    const float* wp = W + cc * 4;
#pragma unroll 2
    for (int k = 0; k < K; k += 4) {
        float4 w0 = *(const float4*)(wp + (size_t)(k + 0) * 64);
        float4 w1 = *(const float4*)(wp + (size_t)(k + 1) * 64);
        float4 w2 = *(const float4*)(wp + (size_t)(k + 2) * 64);
        float4 w3 = *(const float4*)(wp + (size_t)(k + 3) * 64);
        float4 m0 = *(const float4*)(&xs[r0][k]);
        float4 m1 = *(const float4*)(&xs[r0 + 1][k]);

        o0.x = fmaf(m0.x, w0.x, o0.x);
        o0.y = fmaf(m0.x, w0.y, o0.y);
        o0.z = fmaf(m0.x, w0.z, o0.z);
        o0.w = fmaf(m0.x, w0.w, o0.w);
        o0.x = fmaf(m0.y, w1.x, o0.x);
        o0.y = fmaf(m0.y, w1.y, o0.y);
        o0.z = fmaf(m0.y, w1.z, o0.z);
        o0.w = fmaf(m0.y, w1.w, o0.w);
        o0.x = fmaf(m0.z, w2.x, o0.x);
        o0.y = fmaf(m0.z, w2.y, o0.y);
        o0.z = fmaf(m0.z, w2.z, o0.z);
        o0.w = fmaf(m0.z, w2.w, o0.w);
        o0.x = fmaf(m0.w, w3.x, o0.x);
        o0.y = fmaf(m0.w, w3.y, o0.y);
        o0.z = fmaf(m0.w, w3.z, o0.z);
        o0.w = fmaf(m0.w, w3.w, o0.w);

        o1.x = fmaf(m1.x, w0.x, o1.x);
        o1.y = fmaf(m1.x, w0.y, o1.y);
        o1.z = fmaf(m1.x, w0.z, o1.z);
        o1.w = fmaf(m1.x, w0.w, o1.w);
        o1.x = fmaf(m1.y, w1.x, o1.x);
        o1.y = fmaf(m1.y, w1.y, o1.y);
        o1.z = fmaf(m1.y, w1.z, o1.z);
        o1.w = fmaf(m1.y, w1.w, o1.w);
        o1.x = fmaf(m1.z, w2.x, o1.x);
        o1.y = fmaf(m1.z, w2.y, o1.y);
        o1.z = fmaf(m1.z, w2.z, o1.z);
        o1.w = fmaf(m1.z, w2.w, o1.w);
        o1.x = fmaf(m1.w, w3.x, o1.x);
        o1.y = fmaf(m1.w, w3.y, o1.y);
        o1.z = fmaf(m1.w, w3.z, o1.z);
        o1.w = fmaf(m1.w, w3.w, o1.w);
    }

    float4 av = *(const float4*)(a_src + cc * 4);
    float4 dv = *(const float4*)(a_dst + cc * 4);

    if (base < N) {
        union { __half2 h[2]; uint2 u; } pk;
        pk.h[0] = __floats2half2_rn(o0.x, o0.y);
        pk.h[1] = __floats2half2_rn(o0.z, o0.w);
        *(uint2*)(XWh + (size_t)base * 64 + cc * 4) = pk.u;
        float s = o0.x * av.x + o0.y * av.y + o0.z * av.z + o0.w * av.w;
        float d = o0.x * dv.x + o0.y * dv.y + o0.z * dv.z + o0.w * dv.w;
        s += __shfl_xor(s, 1);
        d += __shfl_xor(d, 1);
        if ((cc & 1) == 0) {
            As[base * 8 + (cc >> 1)] = s;
            Ad[base * 8 + (cc >> 1)] = d;
        }
    }
    if (base + 1 < N) {
        union { __half2 h[2]; uint2 u; } pk;
        pk.h[0] = __floats2half2_rn(o1.x, o1.y);
        pk.h[1] = __floats2half2_rn(o1.z, o1.w);
        *(uint2*)(XWh + (size_t)(base + 1) * 64 + cc * 4) = pk.u;
        float s = o1.x * av.x + o1.y * av.y + o1.z * av.z + o1.w * av.w;
        float d = o1.x * dv.x + o1.y * dv.y + o1.z * dv.z + o1.w * dv.w;
        s += __shfl_xor(s, 1);
        d += __shfl_xor(d, 1);
        if ((cc & 1) == 0) {
            As[(base + 1) * 8 + (cc >> 1)] = s;
            Ad[(base + 1) * 8 + (cc >> 1)] = d;
        }
    }
}

// ---------------- Aggregation v3 (layers 1 & 2): fp16 gather ---------------
// Structure of v2 (dedup p-phase + shfl broadcast), but XW rows are fp16
// (128B/row) and OUT optionally fp16 (layer 2 feeds the agg3 gather).

template <bool WITH_A3, bool HALF_OUT>
__global__ __launch_bounds__(256)
void agg_h8c8_v3(const __half* __restrict__ XW, const float* __restrict__ As,
                 const float* __restrict__ Ad, const int* __restrict__ row_ptr,
                 const int* __restrict__ adj, const float* __restrict__ bias,
                 void* __restrict__ OUTv,
                 const float* __restrict__ w_as, const float* __restrict__ w_ad,
                 float* __restrict__ As3, float* __restrict__ Ad3, int N) {
    int wave = threadIdx.x >> 6, lane = threadIdx.x & 63;
    int node = blockIdx.x * 4 + wave;
    if (node >= N) return;
    int beg = row_ptr[node], end = row_ptr[node + 1];
    int eP = lane >> 3, hP = lane & 7;   // p-phase coords
    int hA = lane >> 3;                  // acc-phase head
    float adp = Ad[node * 8 + hP];
    float bv = bias[lane];

    float den_part = 0.f;
    float acc0 = 0.f, acc1 = 0.f;
    int idx = beg;
    for (; idx + 8 <= end; idx += 8) {
        int se = adj[idx + eP];
        float ec = As[(size_t)se * 8 + hP];
        float p = __expf(lrelu(ec + adp));
        den_part += p;
        int s0 = adj[idx + 0], s1 = adj[idx + 1], s2 = adj[idx + 2], s3 = adj[idx + 3];
        int s4 = adj[idx + 4], s5 = adj[idx + 5], s6 = adj[idx + 6], s7 = adj[idx + 7];
        float x0 = __half2float(XW[(size_t)s0 * 64 + lane]);
        float x1 = __half2float(XW[(size_t)s1 * 64 + lane]);
        float x2 = __half2float(XW[(size_t)s2 * 64 + lane]);
        float x3 = __half2float(XW[(size_t)s3 * 64 + lane]);
        float x4 = __half2float(XW[(size_t)s4 * 64 + lane]);
        float x5 = __half2float(XW[(size_t)s5 * 64 + lane]);
        float x6 = __half2float(XW[(size_t)s6 * 64 + lane]);
        float x7 = __half2float(XW[(size_t)s7 * 64 + lane]);
        float p0 = __shfl(p, 0 * 8 + hA);
        float p1 = __shfl(p, 1 * 8 + hA);
        float p2 = __shfl(p, 2 * 8 + hA);
        float p3 = __shfl(p, 3 * 8 + hA);
        float p4 = __shfl(p, 4 * 8 + hA);
        float p5 = __shfl(p, 5 * 8 + hA);
        float p6 = __shfl(p, 6 * 8 + hA);
        float p7 = __shfl(p, 7 * 8 + hA);
        acc0 = fmaf(p0, x0, acc0);
        acc1 = fmaf(p1, x1, acc1);
        acc0 = fmaf(p2, x2, acc0);
        acc1 = fmaf(p3, x3, acc1);
        acc0 = fmaf(p4, x4, acc0);
        acc1 = fmaf(p5, x5, acc1);
        acc0 = fmaf(p6, x6, acc0);
        acc1 = fmaf(p7, x7, acc1);
    }
    int rem = end - idx;
    if (rem > 0) {
        int se = adj[idx + (eP < rem ? eP : rem - 1)];
        float ec = As[(size_t)se * 8 + hP];
        float p = (eP < rem) ? __expf(lrelu(ec + adp)) : 0.f;
        den_part += p;
#pragma unroll
        for (int k = 0; k < 8; ++k) {
            if (k < rem) {  // wave-uniform branch
                int sk = adj[idx + k];
                float xk = __half2float(XW[(size_t)sk * 64 + lane]);
                float pk = __shfl(p, k * 8 + hA);
                acc0 = fmaf(pk, xk, acc0);
            }
        }
    }
    float acc = acc0 + acc1;
    den_part += __shfl_xor(den_part, 8);
    den_part += __shfl_xor(den_part, 16);
    den_part += __shfl_xor(den_part, 32);   // lane holds den[lane&7]
    float den = __shfl(den_part, hA);       // acc lane wants den[hA]

    float v = fmaxf(acc / (den + 1e-16f) + bv, 0.f);
    if (HALF_OUT) ((__half*)OUTv)[(size_t)node * 64 + lane] = __float2half_rn(v);
    else          ((float*)OUTv)[(size_t)node * 64 + lane] = v;

    if (WITH_A3) {
        float s3v = v * w_as[lane];
        float d3v = v * w_ad[lane];
#pragma unroll
        for (int m = 1; m <= 32; m <<= 1) {
            s3v += __shfl_xor(s3v, m);
            d3v += __shfl_xor(d3v, m);
        }
        if (lane == 0) {
            As3[node] = s3v;
            Ad3[node] = d3v;
        }
    }
}

// ---------------- Layer 3 aggregation v3 (H=1): fp16 gather ----------------

__global__ __launch_bounds__(256)
void agg3msg_v3(const __half* __restrict__ H2, const float* __restrict__ As3,
                const float* __restrict__ Ad3, const int* __restrict__ row_ptr,
                const int* __restrict__ adj, float* __restrict__ MSG, int N) {
    int wave = threadIdx.x >> 6, lane = threadIdx.x & 63;
    int node = blockIdx.x * 4 + wave;
    if (node >= N) return;
    int beg = row_ptr[node], end = row_ptr[node + 1];
    float ad = Ad3[node];
    int eP = lane & 7;
    int gbase = lane & 56;  // group-local shuffle base

    float den_part = 0.f;
    float acc0 = 0.f, acc1 = 0.f;
    int idx = beg;
    for (; idx + 8 <= end; idx += 8) {
        int se = adj[idx + eP];
        float p = __expf(lrelu(As3[se] + ad));
        den_part += p;
        int s0 = adj[idx + 0], s1 = adj[idx + 1], s2 = adj[idx + 2], s3 = adj[idx + 3];
        int s4 = adj[idx + 4], s5 = adj[idx + 5], s6 = adj[idx + 6], s7 = adj[idx + 7];
        float x0 = __half2float(H2[(size_t)s0 * 64 + lane]);
        float x1 = __half2float(H2[(size_t)s1 * 64 + lane]);
        float x2 = __half2float(H2[(size_t)s2 * 64 + lane]);
        float x3 = __half2float(H2[(size_t)s3 * 64 + lane]);
        float x4 = __half2float(H2[(size_t)s4 * 64 + lane]);
        float x5 = __half2float(H2[(size_t)s5 * 64 + lane]);
        float x6 = __half2float(H2[(size_t)s6 * 64 + lane]);
        float x7 = __half2float(H2[(size_t)s7 * 64 + lane]);
        float p0 = __shfl(p, gbase + 0);
        float p1 = __shfl(p, gbase + 1);
        float p2 = __shfl(p, gbase + 2);
        float p3 = __shfl(p, gbase + 3);
        float p4 = __shfl(p, gbase + 4);
        float p5 = __shfl(p, gbase + 5);
        float p6 = __shfl(p, gbase + 6);
        float p7 = __shfl(p, gbase + 7);
        acc0 = fmaf(p0, x0, acc0);
        acc1 = fmaf(p1, x1, acc1);
        acc0 = fmaf(p2, x2, acc0);
        acc1 = fmaf(p3, x3, acc1);
        acc0 = fmaf(p4, x4, acc0);
        acc1 = fmaf(p5, x5, acc1);
        acc0 = fmaf(p6, x6, acc0);
        acc1 = fmaf(p7, x7, acc1);
    }
    int rem = end - idx;
    if (rem > 0) {
        int se = adj[idx + (eP < rem ? eP : rem - 1)];
        float p = (eP < rem) ? __expf(lrelu(As3[se] + ad)) : 0.f;
        den_part += p;
#pragma unroll
        for (int k = 0; k < 8; ++k) {
            if (k < rem) {  // wave-uniform branch
                int sk = adj[idx + k];
                float xk = __half2float(H2[(size_t)sk * 64 + lane]);
                float pk = __shfl(p, gbase + k);
                acc0 = fmaf(pk, xk, acc0);
            }
        }
    }
    float acc = acc0 + acc1;
    den_part += __shfl_xor(den_part, 1);
    den_part += __shfl_xor(den_part, 2);
    den_part += __shfl_xor(den_part, 4);  // every lane: full den
    MSG[(size_t)node * 64 + lane] = acc / (den_part + 1e-16f);
}

// ---------------- gemm3 v2: OUT = softmax_pairs(relu(MSG @ W3 + b3)) -------

__global__ __launch_bounds__(256)
void gemm3_kernel(const float* __restrict__ MSG, const float* __restrict__ W3p,
                  const float* __restrict__ bias, float* __restrict__ OUT, int N) {
    __shared__ float msh[4][8][64];
    int wave = threadIdx.x >> 6, lane = threadIdx.x & 63;
    int base = blockIdx.x * 32 + wave * 8;

#pragma unroll
    for (int j = 0; j < 8; ++j) {
        int node = base + j;
        msh[wave][j][lane] = (node < N) ? MSG[(size_t)node * 64 + lane] : 0.f;
    }
    // same-wave LDS RAW: DS pipe in-order, compiler inserts lgkmcnt wait

    int c0 = lane * 4;  // lanes 0..60 carry channels; 61-63 idle
    if (c0 < 242) {
        float o[8][4];
#pragma unroll
        for (int j = 0; j < 8; ++j)
#pragma unroll
            for (int q = 0; q < 4; ++q) o[j][q] = 0.f;

#pragma unroll 4
        for (int k = 0; k < 64; k += 4) {
            float4 w0 = *(const float4*)(W3p + (size_t)(k + 0) * 244 + c0);
            float4 w1 = *(const float4*)(W3p + (size_t)(k + 1) * 244 + c0);
            float4 w2 = *(const float4*)(W3p + (size_t)(k + 2) * 244 + c0);
            float4 w3 = *(const float4*)(W3p + (size_t)(k + 3) * 244 + c0);
#pragma unroll
            for (int j = 0; j < 8; ++j) {
                float4 m = *(const float4*)(&msh[wave][j][k]);
                o[j][0] = fmaf(m.x, w0.x, o[j][0]);
                o[j][1] = fmaf(m.x, w0.y, o[j][1]);
                o[j][2] = fmaf(m.x, w0.z, o[j][2]);
                o[j][3] = fmaf(m.x, w0.w, o[j][3]);
                o[j][0] = fmaf(m.y, w1.x, o[j][0]);
                o[j][1] = fmaf(m.y, w1.y, o[j][1]);
                o[j][2] = fmaf(m.y, w1.z, o[j][2]);
                o[j][3] = fmaf(m.y, w1.w, o[j][3]);
                o[j][0] = fmaf(m.z, w2.x, o[j][0]);
                o[j][1] = fmaf(m.z, w2.y, o[j][1]);
                o[j][2] = fmaf(m.z, w2.z, o[j][2]);
                o[j][3] = fmaf(m.z, w2.w, o[j][3]);
                o[j][0] = fmaf(m.w, w3.x, o[j][0]);
                o[j][1] = fmaf(m.w, w3.y, o[j][1]);
                o[j][2] = fmaf(m.w, w3.z, o[j][2]);
                o[j][3] = fmaf(m.w, w3.w, o[j][3]);
            }
        }

        float b0 = bias[c0], b1v = bias[c0 + 1];
        float b2v = (c0 + 2 < 242) ? bias[c0 + 2] : 0.f;
        float b3v = (c0 + 3 < 242) ? bias[c0 + 3] : 0.f;
#pragma unroll
        for (int j = 0; j < 8; ++j) {
            int node = base + j;
            if (node >= N) break;
            size_t out_base = (size_t)node * 242 + c0;
            float v0 = fmaxf(o[j][0] + b0, 0.f);
            float v1 = fmaxf(o[j][1] + b1v, 0.f);
            float m01 = fmaxf(v0, v1);
            float e0 = __expf(v0 - m01), e1 = __expf(v1 - m01);
            float r01 = 1.f / (e0 + e1);
            OUT[out_base]     = e0 * r01;
            OUT[out_base + 1] = e1 * r01;
            if (c0 + 2 < 242) {
                float v2 = fmaxf(o[j][2] + b2v, 0.f);
                float v3 = fmaxf(o[j][3] + b3v, 0.f);
                float m23 = fmaxf(v2, v3);
                float e2 = __expf(v2 - m23), e3 = __expf(v3 - m23);
                float r23 = 1.f / (e2 + e3);
                OUT[out_base + 2] = e2 * r23;
                OUT[out_base + 3] = e3 * r23;
            }
        }
    }
}

// ---------------- launch ----------------

extern "C" void kernel_launch(void* const* d_in, const int* in_sizes, int n_in,
                              void* d_out, int out_size, void* d_ws, size_t ws_size,
                              hipStream_t stream) {
    const float* x   = (const float*)d_in[0];
    const void*  ei  = d_in[1];
    const float* W1  = (const float*)d_in[2];
    const float* a1s = (const float*)d_in[3];
    const float* a1d = (const float*)d_in[4];
    const float* b1  = (const float*)d_in[5];
    const float* W2  = (const float*)d_in[6];
    const float* a2s = (const float*)d_in[7];
    const float* a2d = (const float*)d_in[8];
    const float* b2  = (const float*)d_in[9];
    const float* W3  = (const float*)d_in[10];
    const float* a3s = (const float*)d_in[11];
    const float* a3d = (const float*)d_in[12];
    const float* b3  = (const float*)d_in[13];
    float* out = (float*)d_out;

    const int N = in_sizes[0] / 128;  // 50000
    const int E = in_sizes[1] / 2;    // 800000

    char* w = (char*)d_ws;
    auto alloc = [&](size_t bytes) {
        char* p = w;
        w += (bytes + 255) & ~(size_t)255;
        return p;
    };
    int*   flag    = (int*)alloc(4);
    int*   row_ptr = (int*)alloc(((size_t)N + 1) * 4);
    int*   adj     = (int*)alloc((size_t)(E + N) * 4);
    int*   btot    = (int*)alloc(256 * 4);
    int*   bbase   = (int*)alloc(257 * 4);
    float* As      = (float*)alloc((size_t)N * 8 * 4);
    float* Ad      = (float*)alloc((size_t)N * 8 * 4);
    float* As3     = (float*)alloc((size_t)N * 4);
    float* Ad3     = (float*)alloc((size_t)N * 4);
    float* w_as    = (float*)alloc(64 * 4);
    float* w_ad    = (float*)alloc(64 * 4);
    float* W3p     = (float*)alloc((size_t)64 * 244 * 4);
    float* bufA    = (float*)alloc((size_t)N * 64 * 4);
    float* bufB    = (float*)alloc((size_t)N * 64 * 4);
    // CSR scratch aliased into bufA (12.8MB): part 6.8MB @0, blkhist 256KB @7MB,
    // blkoff 256KB @7.25MB. All dead before gemm1 first writes bufA.
    int2*   part    = (int2*)bufA;
    int*    blkhist = (int*)((char*)bufA + (size_t)7 * 1024 * 1024);
    int*    blkoff  = (int*)((char*)bufA + (size_t)7 * 1024 * 1024 + 256 * 1024);
    // fp16 buffers aliased into bufA (lifetimes disjoint):
    //   XW1h @ bufA[0:6.4e6)        (gemm1 -> agg1)
    //   XW2h @ bufA[6.4e6:12.8e6)   (gemm2 -> agg2)
    //   h2h  @ bufA[0:6.4e6)        (agg2 -> agg3; XW1h dead)
    __half* XW1h = (__half*)bufA;
    __half* XW2h = (__half*)((char*)bufA + (size_t)N * 64 * 2);
    __half* h2h  = (__half*)bufA;
    float*  msg  = bufB;  // h1 dead after gemm2

    int tot  = E + N;                       // 850000
    int nblk = (tot + CH - 1) / CH;         // 208 <= 256
    int nb   = (N + 255) >> 8;              // 196 <= 256

    // CSR build (bucketed counting sort; includes self-loops)
    detect_kernel<<<1, 64, 0, stream>>>((const int*)ei, flag);
    zero_btot_kernel<<<1, 256, 0, stream>>>(btot);
    histA_kernel<<<nblk, 256, 0, stream>>>(ei, flag, blkhist, btot, E, N);
    bucket_scan_kernel<<<1, 256, 0, stream>>>(btot, bbase, nb, tot);
    blk_scan_kernel<<<nb, 256, 0, stream>>>(blkhist, bbase, blkoff, nblk);
    partC_kernel<<<nblk, 256, 0, stream>>>(ei, flag, blkoff, part, E, N);
    csrD_kernel<<<nb, 256, 0, stream>>>(part, bbase, row_ptr, adj, N);
    w3a_kernel<<<1, 128, 0, stream>>>(W3, a3s, a3d, w_as, w_ad);
    w3pad_kernel<<<(64 * 244 + 255) / 256, 256, 0, stream>>>(W3, W3p);

    int nb4 = (N + 3) / 4;
    int nb32 = (N + 31) / 32;

    // Layer 1: x -> XW1h (fp16), agg -> bufB (h1 fp32)
    gemm_alpha_v5<128><<<nb32, 256, 0, stream>>>(x, W1, a1s, a1d, XW1h, As, Ad, N);
    agg_h8c8_v3<false, false><<<nb4, 256, 0, stream>>>(XW1h, As, Ad, row_ptr, adj, b1,
                                                       bufB, nullptr, nullptr,
                                                       nullptr, nullptr, N);
    // Layer 2: bufB (fp32) -> XW2h (fp16), agg -> h2h (fp16) + As3/Ad3
    gemm_alpha_v5<64><<<nb32, 256, 0, stream>>>(bufB, W2, a2s, a2d, XW2h, As, Ad, N);
    agg_h8c8_v3<true, true><<<nb4, 256, 0, stream>>>(XW2h, As, Ad, row_ptr, adj, b2,
                                                     h2h, w_as, w_ad, As3, Ad3, N);
    // Layer 3: h2h (fp16) -> msg (fp32, bufB), then gemm3 -> out
    agg3msg_v3<<<nb4, 256, 0, stream>>>(h2h, As3, Ad3, row_ptr, adj, msg, N);
    gemm3_kernel<<<nb32, 256, 0, stream>>>(msg, W3p, b3, out, N);
}